// Round 1
// 714.663 us; speedup vs baseline: 1.0341x; 1.0341x over previous
//
#include <hip/hip_runtime.h>
#include <hip/hip_bf16.h>
#include <math.h>

#define IDIM 512
#define HDIM 64

typedef __attribute__((ext_vector_type(8))) short short8;   // 8 bf16 = 4 VGPRs
typedef __attribute__((ext_vector_type(4))) float f32x4;    // MFMA accum
typedef unsigned short u16;
typedef unsigned int u32;

__device__ __forceinline__ float bflo(u32 u) { return __uint_as_float(u << 16); }
__device__ __forceinline__ float bfhi(u32 u) { return __uint_as_float(u & 0xffff0000u); }

// ============ CSR build ============

__global__ __launch_bounds__(256) void k_deg(const int* __restrict__ dst,
                                             int* __restrict__ deg, int E) {
    int e = blockIdx.x * blockDim.x + threadIdx.x;
    if (e < E) atomicAdd(&deg[dst[e]], 1);
}

__global__ __launch_bounds__(256) void k_blocksum(const int* __restrict__ deg,
                                                  int* __restrict__ bsum, int n) {
    __shared__ int sd[256];
    int b = blockIdx.x, tid = threadIdx.x;
    int base = b * 1024 + tid * 4;
    int s = 0;
#pragma unroll
    for (int k = 0; k < 4; k++) {
        int idx = base + k;
        if (idx < n) s += deg[idx];
    }
    sd[tid] = s;
    __syncthreads();
    for (int off = 128; off > 0; off >>= 1) {
        if (tid < off) sd[tid] += sd[tid + off];
        __syncthreads();
    }
    if (tid == 0) bsum[b] = sd[0];
}

__global__ __launch_bounds__(128) void k_scanbsum(const int* __restrict__ bsum,
                                                  int* __restrict__ boff, int B,
                                                  int* __restrict__ rowptr, int n, int E) {
    __shared__ int s[128];
    int t = threadIdx.x;
    int v = (t < B) ? bsum[t] : 0;
    s[t] = v;
    __syncthreads();
    for (int off = 1; off < 128; off <<= 1) {
        int u = (t >= off) ? s[t - off] : 0;
        __syncthreads();
        s[t] += u;
        __syncthreads();
    }
    if (t < B) boff[t] = s[t] - v;
    if (t == 0) rowptr[n] = E;
}

__global__ __launch_bounds__(256) void k_rowptr(const int* __restrict__ deg,
                                                const int* __restrict__ boff,
                                                int* __restrict__ rowptr,
                                                int* __restrict__ cursor,
                                                float* __restrict__ dinv, int n) {
    __shared__ int sd[256];
    int b = blockIdx.x, tid = threadIdx.x;
    int base = b * 1024 + tid * 4;
    int d[4];
    int tt = 0;
#pragma unroll
    for (int k = 0; k < 4; k++) {
        d[k] = (base + k < n) ? deg[base + k] : 0;
        tt += d[k];
    }
    sd[tid] = tt;
    __syncthreads();
    for (int off = 1; off < 256; off <<= 1) {
        int v = 0;
        if (tid >= off) v = sd[tid - off];
        __syncthreads();
        sd[tid] += v;
        __syncthreads();
    }
    int run = boff[b] + sd[tid] - tt;
#pragma unroll
    for (int k = 0; k < 4; k++) {
        if (base + k < n) {
            rowptr[base + k] = run;
            cursor[base + k] = run;
            dinv[base + k] = rsqrtf((float)d[k] + 1.0f);
            run += d[k];
        }
    }
}

__global__ __launch_bounds__(256) void k_build(const int* __restrict__ src,
                                               const int* __restrict__ dst,
                                               int* __restrict__ cursor,
                                               int* __restrict__ srcs, int E) {
    int e = blockIdx.x * blockDim.x + threadIdx.x;
    if (e >= E) return;
    int p = atomicAdd(&cursor[dst[e]], 1);
    srcs[p] = src[e];
}

// ============ W1 -> bf16 B^T table ============
__global__ __launch_bounds__(256) void k_prepB(const float* __restrict__ W1,
                                               short* __restrict__ Btg) {
    int id = blockIdx.x * 256 + threadIdx.x;
    if (id >= IDIM * HDIM) return;
    int k = id >> 6, nn = id & 63;
    __hip_bfloat16 b = __float2bfloat16(W1[id]);
    Btg[nn * IDIM + k] = *(short*)&b;
}

// ============ [Wmu|Wvar] -> bf16 hi/lo B^T tables [128 cols][64 k] ============
__global__ __launch_bounds__(256) void k_prepW2(const float* __restrict__ Wmu,
                                                const float* __restrict__ Wvar,
                                                short* __restrict__ Whi,
                                                short* __restrict__ Wlo) {
    int id = blockIdx.x * 256 + threadIdx.x;
    if (id >= 128 * 64) return;
    int c = id >> 6;      // output column 0..127 (0..63 = mu, 64..127 = var)
    int k = id & 63;
    float wv = (c < 64) ? Wmu[k * 64 + c] : Wvar[k * 64 + (c - 64)];
    __hip_bfloat16 h = __float2bfloat16(wv);
    float hf = __bfloat162float(h);
    __hip_bfloat16 l = __float2bfloat16(wv - hf);
    Whi[c * 64 + k] = *(short*)&h;
    Wlo[c * 64 + k] = *(short*)&l;
}

// ============ GEMM1 (bf16 MFMA): g1 = bf16((x @ W1) * dinv) ============
#define GM 128
#define KC 128
#define APAD 8
__global__ __launch_bounds__(256) void k_gemm1(const float* __restrict__ x,
                                               const short* __restrict__ Btg,
                                               const float* __restrict__ dinv,
                                               u16* __restrict__ g1, int n) {
    __shared__ short As[GM][KC + APAD];
    __shared__ short Bs[HDIM][KC + APAD];
    int tid = threadIdx.x;
    int row0 = blockIdx.x * GM;
    int w = tid >> 6, lane = tid & 63;
    int m = lane & 15, kb = lane >> 4;

    f32x4 acc[2][4];
#pragma unroll
    for (int rb = 0; rb < 2; rb++)
#pragma unroll
        for (int nt = 0; nt < 4; nt++) acc[rb][nt] = (f32x4){0.f, 0.f, 0.f, 0.f};

    for (int kc = 0; kc < IDIM; kc += KC) {
        __syncthreads();
#pragma unroll
        for (int i = 0; i < 16; i++) {
            int idx = tid + i * 256;
            int r = idx >> 5;
            int c4 = idx & 31;
            int grow = row0 + r;
            float4 v = make_float4(0.f, 0.f, 0.f, 0.f);
            if (grow < n) v = *(const float4*)&x[(size_t)grow * IDIM + kc + c4 * 4];
            __hip_bfloat162 h0 = __float22bfloat162_rn(make_float2(v.x, v.y));
            __hip_bfloat162 h1 = __float22bfloat162_rn(make_float2(v.z, v.w));
            int2 p;
            p.x = *(int*)&h0;
            p.y = *(int*)&h1;
            *(int2*)&As[r][c4 * 4] = p;
        }
#pragma unroll
        for (int i = 0; i < 4; i++) {
            int idx = tid + i * 256;
            int r = idx >> 4;
            int u8 = idx & 15;
            float4 v = *(const float4*)&Btg[(size_t)r * IDIM + kc + u8 * 8];
            *(float4*)&Bs[r][u8 * 8] = v;
        }
        __syncthreads();
#pragma unroll
        for (int ks = 0; ks < KC; ks += 32) {
            short8 a0 = *(const short8*)&As[w * 32 + m][ks + kb * 8];
            short8 a1 = *(const short8*)&As[w * 32 + 16 + m][ks + kb * 8];
            short8 b0 = *(const short8*)&Bs[m][ks + kb * 8];
            short8 b1 = *(const short8*)&Bs[16 + m][ks + kb * 8];
            short8 b2 = *(const short8*)&Bs[32 + m][ks + kb * 8];
            short8 b3 = *(const short8*)&Bs[48 + m][ks + kb * 8];
            acc[0][0] = __builtin_amdgcn_mfma_f32_16x16x32_bf16(a0, b0, acc[0][0], 0, 0, 0);
            acc[0][1] = __builtin_amdgcn_mfma_f32_16x16x32_bf16(a0, b1, acc[0][1], 0, 0, 0);
            acc[0][2] = __builtin_amdgcn_mfma_f32_16x16x32_bf16(a0, b2, acc[0][2], 0, 0, 0);
            acc[0][3] = __builtin_amdgcn_mfma_f32_16x16x32_bf16(a0, b3, acc[0][3], 0, 0, 0);
            acc[1][0] = __builtin_amdgcn_mfma_f32_16x16x32_bf16(a1, b0, acc[1][0], 0, 0, 0);
            acc[1][1] = __builtin_amdgcn_mfma_f32_16x16x32_bf16(a1, b1, acc[1][1], 0, 0, 0);
            acc[1][2] = __builtin_amdgcn_mfma_f32_16x16x32_bf16(a1, b2, acc[1][2], 0, 0, 0);
            acc[1][3] = __builtin_amdgcn_mfma_f32_16x16x32_bf16(a1, b3, acc[1][3], 0, 0, 0);
        }
    }
#pragma unroll
    for (int rb = 0; rb < 2; rb++) {
        int rbase = row0 + w * 32 + rb * 16 + kb * 4;
#pragma unroll
        for (int reg = 0; reg < 4; reg++) {
            int grow = rbase + reg;
            if (grow < n) {
                float dv = dinv[grow];
#pragma unroll
                for (int nt = 0; nt < 4; nt++) {
                    __hip_bfloat16 b = __float2bfloat16(acc[rb][nt][reg] * dv);
                    g1[(size_t)grow * HDIM + nt * 16 + m] = *(u16*)&b;
                }
            }
        }
    }
}

// ============ layer-1 gather (bf16 tables) ============
// wave per node; 8 lane-groups of 8; lane&7 = 16B feature chunk (8 bf16)
__global__ __launch_bounds__(256) void k_gather1(const int* __restrict__ rowptr,
                                                 const int* __restrict__ srcs,
                                                 const float* __restrict__ dinv,
                                                 const u16* __restrict__ g1,
                                                 const float* __restrict__ b1,
                                                 u16* __restrict__ g2, int n) {
    int tid = threadIdx.x;
    int r = tid >> 6, lane = tid & 63;
    int grp = lane >> 3, q = lane & 7;
    int i = blockIdx.x * 4 + r;
    if (i >= n) return;
    int beg = rowptr[i], end = rowptr[i + 1];
    float a[8];
#pragma unroll
    for (int k = 0; k < 8; k++) a[k] = 0.f;
    int j = beg + grp;
    for (; j + 8 < end; j += 16) {
        int s0 = srcs[j];
        int s1 = srcs[j + 8];
        uint4 u0 = *(const uint4*)&g1[(size_t)s0 * HDIM + q * 8];
        uint4 u1 = *(const uint4*)&g1[(size_t)s1 * HDIM + q * 8];
        a[0] += bflo(u0.x) + bflo(u1.x); a[1] += bfhi(u0.x) + bfhi(u1.x);
        a[2] += bflo(u0.y) + bflo(u1.y); a[3] += bfhi(u0.y) + bfhi(u1.y);
        a[4] += bflo(u0.z) + bflo(u1.z); a[5] += bfhi(u0.z) + bfhi(u1.z);
        a[6] += bflo(u0.w) + bflo(u1.w); a[7] += bfhi(u0.w) + bfhi(u1.w);
    }
    if (j < end) {
        int s0 = srcs[j];
        uint4 u0 = *(const uint4*)&g1[(size_t)s0 * HDIM + q * 8];
        a[0] += bflo(u0.x); a[1] += bfhi(u0.x);
        a[2] += bflo(u0.y); a[3] += bfhi(u0.y);
        a[4] += bflo(u0.z); a[5] += bfhi(u0.z);
        a[6] += bflo(u0.w); a[7] += bfhi(u0.w);
    }
#pragma unroll
    for (int k = 0; k < 8; k++) {
        a[k] += __shfl_xor(a[k], 8);
        a[k] += __shfl_xor(a[k], 16);
        a[k] += __shfl_xor(a[k], 32);
    }
    if (grp == 0) {
        uint4 us = *(const uint4*)&g1[(size_t)i * HDIM + q * 8];
        float s0 = bflo(us.x), s1 = bfhi(us.x), s2 = bflo(us.y), s3 = bfhi(us.y);
        float s4 = bflo(us.z), s5 = bfhi(us.z), s6 = bflo(us.w), s7 = bfhi(us.w);
        float4 bv0 = *(const float4*)&b1[q * 8];
        float4 bv1 = *(const float4*)&b1[q * 8 + 4];
        float di = dinv[i];
        float o0 = fmaxf(di * (a[0] + s0) + bv0.x, 0.f) * di;
        float o1 = fmaxf(di * (a[1] + s1) + bv0.y, 0.f) * di;
        float o2 = fmaxf(di * (a[2] + s2) + bv0.z, 0.f) * di;
        float o3 = fmaxf(di * (a[3] + s3) + bv0.w, 0.f) * di;
        float o4 = fmaxf(di * (a[4] + s4) + bv1.x, 0.f) * di;
        float o5 = fmaxf(di * (a[5] + s5) + bv1.y, 0.f) * di;
        float o6 = fmaxf(di * (a[6] + s6) + bv1.z, 0.f) * di;
        float o7 = fmaxf(di * (a[7] + s7) + bv1.w, 0.f) * di;
        __hip_bfloat162 p0 = __float22bfloat162_rn(make_float2(o0, o1));
        __hip_bfloat162 p1 = __float22bfloat162_rn(make_float2(o2, o3));
        __hip_bfloat162 p2 = __float22bfloat162_rn(make_float2(o4, o5));
        __hip_bfloat162 p3 = __float22bfloat162_rn(make_float2(o6, o7));
        uint4 w;
        w.x = *(u32*)&p0; w.y = *(u32*)&p1; w.z = *(u32*)&p2; w.w = *(u32*)&p3;
        *(uint4*)&g2[(size_t)i * HDIM + q * 8] = w;
    }
}

// ============ layer-2 gather: pure aggregation, writes h_agg fp32 ============
__global__ __launch_bounds__(256) void k_gather2(const int* __restrict__ rowptr,
                                                 const int* __restrict__ srcs,
                                                 const float* __restrict__ dinv,
                                                 const u16* __restrict__ g2,
                                                 float* __restrict__ hagg, int n) {
    int tid = threadIdx.x;
    int r = tid >> 6, lane = tid & 63;
    int grp = lane >> 3, q = lane & 7;
    int i = blockIdx.x * 4 + r;
    if (i >= n) return;
    int beg = rowptr[i], end = rowptr[i + 1];
    float a[8];
#pragma unroll
    for (int k = 0; k < 8; k++) a[k] = 0.f;
    int j = beg + grp;
    for (; j + 8 < end; j += 16) {
        int s0 = srcs[j];
        int s1 = srcs[j + 8];
        uint4 u0 = *(const uint4*)&g2[(size_t)s0 * HDIM + q * 8];
        uint4 u1 = *(const uint4*)&g2[(size_t)s1 * HDIM + q * 8];
        a[0] += bflo(u0.x) + bflo(u1.x); a[1] += bfhi(u0.x) + bfhi(u1.x);
        a[2] += bflo(u0.y) + bflo(u1.y); a[3] += bfhi(u0.y) + bfhi(u1.y);
        a[4] += bflo(u0.z) + bflo(u1.z); a[5] += bfhi(u0.z) + bfhi(u1.z);
        a[6] += bflo(u0.w) + bflo(u1.w); a[7] += bfhi(u0.w) + bfhi(u1.w);
    }
    if (j < end) {
        int s0 = srcs[j];
        uint4 u0 = *(const uint4*)&g2[(size_t)s0 * HDIM + q * 8];
        a[0] += bflo(u0.x); a[1] += bfhi(u0.x);
        a[2] += bflo(u0.y); a[3] += bfhi(u0.y);
        a[4] += bflo(u0.z); a[5] += bfhi(u0.z);
        a[6] += bflo(u0.w); a[7] += bfhi(u0.w);
    }
#pragma unroll
    for (int k = 0; k < 8; k++) {
        a[k] += __shfl_xor(a[k], 8);
        a[k] += __shfl_xor(a[k], 16);
        a[k] += __shfl_xor(a[k], 32);
    }
    if (grp == 0) {
        uint4 us = *(const uint4*)&g2[(size_t)i * HDIM + q * 8];
        float di = dinv[i];
        float4 o0, o1;
        o0.x = di * (a[0] + bflo(us.x));
        o0.y = di * (a[1] + bfhi(us.x));
        o0.z = di * (a[2] + bflo(us.y));
        o0.w = di * (a[3] + bfhi(us.y));
        o1.x = di * (a[4] + bflo(us.z));
        o1.y = di * (a[5] + bfhi(us.z));
        o1.z = di * (a[6] + bflo(us.w));
        o1.w = di * (a[7] + bfhi(us.w));
        *(float4*)&hagg[(size_t)i * HDIM + q * 8] = o0;
        *(float4*)&hagg[(size_t)i * HDIM + q * 8 + 4] = o1;
    }
}

// ============ GEMM2 (bf16 MFMA, split hi/lo for ~fp32 accuracy) + epilogue ====
// C[row, c] = hagg[row,:] @ Wcat[:, c];  c<64: z_mean (+bmu), c>=64: softplus var
// Split product: A_hi*W_hi + A_lo*W_hi + A_hi*W_lo  (residual A_lo*W_lo ~ 2^-18)
__global__ __launch_bounds__(256) void k_gemm2(const float* __restrict__ hagg,
                                               const short* __restrict__ Whi,
                                               const short* __restrict__ Wlo,
                                               const float* __restrict__ bmu,
                                               const float* __restrict__ bvar,
                                               const float* __restrict__ eps,
                                               float* __restrict__ out, int n) {
    int tid = threadIdx.x;
    int w = tid >> 6, lane = tid & 63;
    int m = lane & 15, kb = lane >> 4;
    int row0 = blockIdx.x * 128 + w * 32;

    // A fragments direct from global: rows row0+rb*16+m, k = ks*32+kb*8 .. +8
    short8 ah[2][2], al[2][2];
#pragma unroll
    for (int rb = 0; rb < 2; rb++) {
#pragma unroll
        for (int ks = 0; ks < 2; ks++) {
            int grow = row0 + rb * 16 + m;
            float v[8];
            if (grow < n) {
                const float* base = &hagg[(size_t)grow * HDIM + ks * 32 + kb * 8];
                float4 v0 = *(const float4*)base;
                float4 v1 = *(const float4*)(base + 4);
                v[0] = v0.x; v[1] = v0.y; v[2] = v0.z; v[3] = v0.w;
                v[4] = v1.x; v[5] = v1.y; v[6] = v1.z; v[7] = v1.w;
            } else {
#pragma unroll
                for (int jj = 0; jj < 8; jj++) v[jj] = 0.f;
            }
#pragma unroll
            for (int jj = 0; jj < 8; jj++) {
                __hip_bfloat16 h = __float2bfloat16(v[jj]);
                float hf = __bfloat162float(h);
                __hip_bfloat16 l = __float2bfloat16(v[jj] - hf);
                ah[rb][ks][jj] = *(short*)&h;
                al[rb][ks][jj] = *(short*)&l;
            }
        }
    }

    f32x4 acc[2][8];
#pragma unroll
    for (int rb = 0; rb < 2; rb++)
#pragma unroll
        for (int nt = 0; nt < 8; nt++) acc[rb][nt] = (f32x4){0.f, 0.f, 0.f, 0.f};

#pragma unroll
    for (int nt = 0; nt < 8; nt++) {
#pragma unroll
        for (int ks = 0; ks < 2; ks++) {
            const short* bbase = &Whi[(size_t)(nt * 16 + m) * HDIM + ks * 32 + kb * 8];
            const short* lbase = &Wlo[(size_t)(nt * 16 + m) * HDIM + ks * 32 + kb * 8];
            short8 bh = *(const short8*)bbase;
            short8 bl = *(const short8*)lbase;
#pragma unroll
            for (int rb = 0; rb < 2; rb++) {
                acc[rb][nt] = __builtin_amdgcn_mfma_f32_16x16x32_bf16(ah[rb][ks], bh, acc[rb][nt], 0, 0, 0);
                acc[rb][nt] = __builtin_amdgcn_mfma_f32_16x16x32_bf16(al[rb][ks], bh, acc[rb][nt], 0, 0, 0);
                acc[rb][nt] = __builtin_amdgcn_mfma_f32_16x16x32_bf16(ah[rb][ks], bl, acc[rb][nt], 0, 0, 0);
            }
        }
    }

    size_t nh = (size_t)n * HDIM;
#pragma unroll
    for (int rb = 0; rb < 2; rb++) {
#pragma unroll
        for (int nt = 0; nt < 4; nt++) {
            int c = nt * 16 + m;
            float bm = bmu[c], bv = bvar[c];
#pragma unroll
            for (int reg = 0; reg < 4; reg++) {
                int grow = row0 + rb * 16 + kb * 4 + reg;
                if (grow < n) {
                    float mu = acc[rb][nt][reg] + bm;
                    float va = acc[rb][nt + 4][reg] + bv;
                    float zv = fmaxf(va, 0.f) + log1pf(expf(-fabsf(va)));
                    size_t o = (size_t)grow * HDIM + c;
                    float z = mu + zv * eps[o];
                    out[o] = mu;
                    out[nh + o] = zv;
                    out[2 * nh + o] = z;
                }
            }
        }
    }
}

extern "C" void kernel_launch(void* const* d_in, const int* in_sizes, int n_in,
                              void* d_out, int out_size, void* d_ws, size_t ws_size,
                              hipStream_t stream) {
    const float* x    = (const float*)d_in[0];
    const int*   ei   = (const int*)d_in[1];
    const float* W1   = (const float*)d_in[2];
    const float* b1   = (const float*)d_in[3];
    const float* Wmu  = (const float*)d_in[4];
    const float* bmu  = (const float*)d_in[5];
    const float* Wvar = (const float*)d_in[6];
    const float* bvar = (const float*)d_in[7];
    const float* eps  = (const float*)d_in[8];
    float* out = (float*)d_out;

    int n = in_sizes[0] / IDIM;
    int E = in_sizes[1] / 2;
    const int* src = ei;
    const int* dst = ei + E;

    // workspace layout (16B-aligned chunks first; hagg fp32 aliases dead g1)
    char* p = (char*)d_ws;
    u16* bufB   = (u16*)p;               p += (size_t)n * HDIM * 2;      // g2 [n*64] bf16
    float* hagg = (float*)p;             p += (size_t)n * HDIM * 4;      // h_agg fp32 (reuses g1 space)
    u16* bufA   = (u16*)hagg;                                            // g1 [n*64] bf16 (dead after gather1)
    int* srcs   = (int*)p;               p += (size_t)E * 4;             // CSR cols
    short* Btg  = (short*)p;             p += (size_t)IDIM * HDIM * 2;   // W1^T bf16
    short* W2hi = (short*)p;             p += (size_t)128 * HDIM * 2;    // [Wmu|Wvar]^T hi
    short* W2lo = (short*)p;             p += (size_t)128 * HDIM * 2;    // [Wmu|Wvar]^T lo
    int* rowptr = (int*)p;               p += (size_t)(n + 1) * 4;
    int* cursor = (int*)p;               p += (size_t)n * 4;
    float* dinv = (float*)p;             p += (size_t)n * 4;
    int* bsum   = (int*)p;               p += 128 * 4;
    int* boff   = (int*)p;               p += 128 * 4;

    int B = (n + 1023) / 1024;

    // --- CSR build ---
    hipMemsetAsync(cursor, 0, (size_t)n * sizeof(int), stream);
    k_deg<<<(E + 255) / 256, 256, 0, stream>>>(dst, cursor, E);
    k_blocksum<<<B, 256, 0, stream>>>(cursor, bsum, n);
    k_scanbsum<<<1, 128, 0, stream>>>(bsum, boff, B, rowptr, n, E);
    k_rowptr<<<B, 256, 0, stream>>>(cursor, boff, rowptr, cursor, dinv, n);
    k_build<<<(E + 255) / 256, 256, 0, stream>>>(src, dst, cursor, srcs, E);

    // --- weight prep ---
    k_prepB<<<(IDIM * HDIM + 255) / 256, 256, 0, stream>>>(W1, Btg);
    k_prepW2<<<(128 * HDIM + 255) / 256, 256, 0, stream>>>(Wmu, Wvar, W2hi, W2lo);

    // --- layer 1 ---
    k_gemm1<<<(n + GM - 1) / GM, 256, 0, stream>>>(x, Btg, dinv, bufA, n);
    k_gather1<<<(n + 3) / 4, 256, 0, stream>>>(rowptr, srcs, dinv, bufA, b1, bufB, n);

    // --- layer 2: aggregate, then MFMA epilogue GEMM ---
    k_gather2<<<(n + 3) / 4, 256, 0, stream>>>(rowptr, srcs, dinv, bufB, hagg, n);
    k_gemm2<<<(n + 127) / 128, 256, 0, stream>>>(hagg, W2hi, W2lo, bmu, bvar, eps, out, n);
}

// Round 2
// 573.979 us; speedup vs baseline: 1.2876x; 1.2451x over previous
//
#include <hip/hip_runtime.h>
#include <hip/hip_bf16.h>
#include <math.h>

#define IDIM 512
#define HDIM 64

// coarse bucketing for CSR build
#define CB_SH 9
#define CB_NODES 512          // 1 << CB_SH
#define PCHUNK 4096           // edges per partition block

typedef __attribute__((ext_vector_type(8))) short short8;   // 8 bf16 = 4 VGPRs
typedef __attribute__((ext_vector_type(4))) float f32x4;    // MFMA accum
typedef unsigned short u16;
typedef unsigned int u32;

__device__ __forceinline__ float bflo(u32 u) { return __uint_as_float(u << 16); }
__device__ __forceinline__ float bfhi(u32 u) { return __uint_as_float(u & 0xffff0000u); }

// ============ CSR build: coarse-bucket counting sort ============
// Replaces k_deg/k_blocksum/k_scanbsum/k_rowptr/k_build.
// Eliminates the 105 MB of partial-cacheline writebacks from random 4B scatter.

// (1) global histogram of dst >> CB_SH
__global__ __launch_bounds__(256) void k_chist(const int* __restrict__ dst,
                                               int* __restrict__ gHist, int E, int NB) {
    __shared__ int h[1024];
    int tid = threadIdx.x;
    for (int i = tid; i < NB; i += 256) h[i] = 0;
    __syncthreads();
    int stride = gridDim.x * 256;
    for (int e = blockIdx.x * 256 + tid; e < E; e += stride)
        atomicAdd(&h[dst[e] >> CB_SH], 1);
    __syncthreads();
    for (int i = tid; i < NB; i += 256)
        if (h[i]) atomicAdd(&gHist[i], h[i]);
}

// (2) exclusive scan of NB (<=1024) bucket counts; init gcur; set sentinels
__global__ __launch_bounds__(256) void k_cscan(const int* __restrict__ gHist,
                                               int* __restrict__ bucketBase,
                                               int* __restrict__ gcur, int NB,
                                               int* __restrict__ rowptr, int n, int E) {
    __shared__ int ss[256];
    int tid = threadIdx.x;
    int v[4];
    int s = 0;
#pragma unroll
    for (int k = 0; k < 4; k++) {
        int i = tid * 4 + k;
        v[k] = (i < NB) ? gHist[i] : 0;
        s += v[k];
    }
    ss[tid] = s;
    __syncthreads();
    for (int o = 1; o < 256; o <<= 1) {
        int u = (tid >= o) ? ss[tid - o] : 0;
        __syncthreads();
        ss[tid] += u;
        __syncthreads();
    }
    int ex = ss[tid] - s;
#pragma unroll
    for (int k = 0; k < 4; k++) {
        int i = tid * 4 + k;
        if (i < NB) { bucketBase[i] = ex; gcur[i] = ex; }
        ex += v[k];
    }
    if (tid == 0) { bucketBase[NB] = E; rowptr[n] = E; }
}

// (3) partition edges into bucket-contiguous tmp (pairs). Each block reserves
// per-bucket segments with ONE global atomic per bucket, then writes into its
// private ~21-entry segments -> full-line writebacks instead of 64B-per-4B.
__global__ __launch_bounds__(256) void k_partition(const int* __restrict__ src,
                                                   const int* __restrict__ dst,
                                                   int* __restrict__ gcur,
                                                   int2* __restrict__ tmp, int E, int NB) {
    __shared__ int h[1024];
    __shared__ int base[1024];
    int tid = threadIdx.x;
    int e0 = blockIdx.x * PCHUNK;
    int e1 = min(e0 + PCHUNK, E);
    for (int i = tid; i < NB; i += 256) h[i] = 0;
    __syncthreads();
    for (int e = e0 + tid; e < e1; e += 256)
        atomicAdd(&h[dst[e] >> CB_SH], 1);
    __syncthreads();
    for (int i = tid; i < NB; i += 256) {
        int c = h[i];
        base[i] = c ? atomicAdd(&gcur[i], c) : 0;
        h[i] = 0;   // reuse as running cursor
    }
    __syncthreads();
    for (int e = e0 + tid; e < e1; e += 256) {
        int d = dst[e];
        int b = d >> CB_SH;
        int r = atomicAdd(&h[b], 1);
        tmp[base[b] + r] = make_int2(src[e], d);
    }
}

// (4) per-bucket finalize: LDS histogram+scan over 512 local nodes, write
// rowptr/dinv, scatter srcs into the bucket's contiguous CSR region (L2-local).
__global__ __launch_bounds__(256) void k_finalize(const int2* __restrict__ tmp,
                                                  const int* __restrict__ bucketBase,
                                                  int* __restrict__ rowptr,
                                                  float* __restrict__ dinv,
                                                  int* __restrict__ srcs, int n) {
    __shared__ int hist[CB_NODES];
    __shared__ int off[CB_NODES];
    __shared__ int ss[256];
    int b = blockIdx.x;
    int tid = threadIdx.x;
    int node0 = b << CB_SH;
    int nloc = min(CB_NODES, n - node0);
    int e0 = bucketBase[b], e1 = bucketBase[b + 1];
    hist[tid] = 0;
    hist[tid + 256] = 0;
    __syncthreads();
    for (int e = e0 + tid; e < e1; e += 256)
        atomicAdd(&hist[tmp[e].y - node0], 1);
    __syncthreads();
    // exclusive scan over 512 (2 elems/thread)
    int v0 = hist[2 * tid], v1 = hist[2 * tid + 1];
    int ps = v0 + v1;
    ss[tid] = ps;
    __syncthreads();
    for (int o = 1; o < 256; o <<= 1) {
        int u = (tid >= o) ? ss[tid - o] : 0;
        __syncthreads();
        ss[tid] += u;
        __syncthreads();
    }
    int ex = ss[tid] - ps;
    off[2 * tid] = ex;
    off[2 * tid + 1] = ex + v0;
    __syncthreads();
    for (int i = tid; i < nloc; i += 256) {
        rowptr[node0 + i] = e0 + off[i];
        dinv[node0 + i] = rsqrtf((float)hist[i] + 1.0f);
    }
    __syncthreads();
    for (int e = e0 + tid; e < e1; e += 256) {
        int2 p = tmp[e];
        int r = atomicAdd(&off[p.y - node0], 1);
        srcs[e0 + r] = p.x;
    }
}

// ============ W1 -> bf16 B^T table ============
__global__ __launch_bounds__(256) void k_prepB(const float* __restrict__ W1,
                                               short* __restrict__ Btg) {
    int id = blockIdx.x * 256 + threadIdx.x;
    if (id >= IDIM * HDIM) return;
    int k = id >> 6, nn = id & 63;
    __hip_bfloat16 b = __float2bfloat16(W1[id]);
    Btg[nn * IDIM + k] = *(short*)&b;
}

// ============ [Wmu|Wvar] -> bf16 hi/lo B^T tables [128 cols][64 k] ============
__global__ __launch_bounds__(256) void k_prepW2(const float* __restrict__ Wmu,
                                                const float* __restrict__ Wvar,
                                                short* __restrict__ Whi,
                                                short* __restrict__ Wlo) {
    int id = blockIdx.x * 256 + threadIdx.x;
    if (id >= 128 * 64) return;
    int c = id >> 6;      // output column 0..127 (0..63 = mu, 64..127 = var)
    int k = id & 63;
    float wv = (c < 64) ? Wmu[k * 64 + c] : Wvar[k * 64 + (c - 64)];
    __hip_bfloat16 h = __float2bfloat16(wv);
    float hf = __bfloat162float(h);
    __hip_bfloat16 l = __float2bfloat16(wv - hf);
    Whi[c * 64 + k] = *(short*)&h;
    Wlo[c * 64 + k] = *(short*)&l;
}

// ============ GEMM1 (bf16 MFMA): g1 = bf16((x @ W1) * dinv) ============
// KC=64: 27.6KB LDS -> 5 blocks/CU (20 waves/CU) vs KC=128's 3 blocks (12 waves)
#define GM 128
#define KC 64
#define APAD 8
__global__ __launch_bounds__(256) void k_gemm1(const float* __restrict__ x,
                                               const short* __restrict__ Btg,
                                               const float* __restrict__ dinv,
                                               u16* __restrict__ g1, int n) {
    __shared__ short As[GM][KC + APAD];
    __shared__ short Bs[HDIM][KC + APAD];
    int tid = threadIdx.x;
    int row0 = blockIdx.x * GM;
    int w = tid >> 6, lane = tid & 63;
    int m = lane & 15, kb = lane >> 4;

    f32x4 acc[2][4];
#pragma unroll
    for (int rb = 0; rb < 2; rb++)
#pragma unroll
        for (int nt = 0; nt < 4; nt++) acc[rb][nt] = (f32x4){0.f, 0.f, 0.f, 0.f};

    for (int kc = 0; kc < IDIM; kc += KC) {
        __syncthreads();
        // A tile: 128 rows x 64 cols fp32 -> bf16; 8 float4 per thread
#pragma unroll
        for (int i = 0; i < 8; i++) {
            int idx = tid + i * 256;
            int r = idx >> 4;
            int c4 = idx & 15;
            int grow = row0 + r;
            float4 v = make_float4(0.f, 0.f, 0.f, 0.f);
            if (grow < n) v = *(const float4*)&x[(size_t)grow * IDIM + kc + c4 * 4];
            __hip_bfloat162 h0 = __float22bfloat162_rn(make_float2(v.x, v.y));
            __hip_bfloat162 h1 = __float22bfloat162_rn(make_float2(v.z, v.w));
            int2 p;
            p.x = *(int*)&h0;
            p.y = *(int*)&h1;
            *(int2*)&As[r][c4 * 4] = p;
        }
        // B tile: 64 rows x 64 cols bf16; 2 float4 (8 bf16) per thread
#pragma unroll
        for (int i = 0; i < 2; i++) {
            int idx = tid + i * 256;
            int r = idx >> 3;
            int u8 = idx & 7;
            float4 v = *(const float4*)&Btg[(size_t)r * IDIM + kc + u8 * 8];
            *(float4*)&Bs[r][u8 * 8] = v;
        }
        __syncthreads();
#pragma unroll
        for (int ks = 0; ks < KC; ks += 32) {
            short8 a0 = *(const short8*)&As[w * 32 + m][ks + kb * 8];
            short8 a1 = *(const short8*)&As[w * 32 + 16 + m][ks + kb * 8];
            short8 b0 = *(const short8*)&Bs[m][ks + kb * 8];
            short8 b1 = *(const short8*)&Bs[16 + m][ks + kb * 8];
            short8 b2 = *(const short8*)&Bs[32 + m][ks + kb * 8];
            short8 b3 = *(const short8*)&Bs[48 + m][ks + kb * 8];
            acc[0][0] = __builtin_amdgcn_mfma_f32_16x16x32_bf16(a0, b0, acc[0][0], 0, 0, 0);
            acc[0][1] = __builtin_amdgcn_mfma_f32_16x16x32_bf16(a0, b1, acc[0][1], 0, 0, 0);
            acc[0][2] = __builtin_amdgcn_mfma_f32_16x16x32_bf16(a0, b2, acc[0][2], 0, 0, 0);
            acc[0][3] = __builtin_amdgcn_mfma_f32_16x16x32_bf16(a0, b3, acc[0][3], 0, 0, 0);
            acc[1][0] = __builtin_amdgcn_mfma_f32_16x16x32_bf16(a1, b0, acc[1][0], 0, 0, 0);
            acc[1][1] = __builtin_amdgcn_mfma_f32_16x16x32_bf16(a1, b1, acc[1][1], 0, 0, 0);
            acc[1][2] = __builtin_amdgcn_mfma_f32_16x16x32_bf16(a1, b2, acc[1][2], 0, 0, 0);
            acc[1][3] = __builtin_amdgcn_mfma_f32_16x16x32_bf16(a1, b3, acc[1][3], 0, 0, 0);
        }
    }
#pragma unroll
    for (int rb = 0; rb < 2; rb++) {
        int rbase = row0 + w * 32 + rb * 16 + kb * 4;
#pragma unroll
        for (int reg = 0; reg < 4; reg++) {
            int grow = rbase + reg;
            if (grow < n) {
                float dv = dinv[grow];
#pragma unroll
                for (int nt = 0; nt < 4; nt++) {
                    __hip_bfloat16 b = __float2bfloat16(acc[rb][nt][reg] * dv);
                    g1[(size_t)grow * HDIM + nt * 16 + m] = *(u16*)&b;
                }
            }
        }
    }
}

// ============ layer-1 gather (bf16 tables) ============
__global__ __launch_bounds__(256) void k_gather1(const int* __restrict__ rowptr,
                                                 const int* __restrict__ srcs,
                                                 const float* __restrict__ dinv,
                                                 const u16* __restrict__ g1,
                                                 const float* __restrict__ b1,
                                                 u16* __restrict__ g2, int n) {
    int tid = threadIdx.x;
    int r = tid >> 6, lane = tid & 63;
    int grp = lane >> 3, q = lane & 7;
    int i = blockIdx.x * 4 + r;
    if (i >= n) return;
    int beg = rowptr[i], end = rowptr[i + 1];
    float a[8];
#pragma unroll
    for (int k = 0; k < 8; k++) a[k] = 0.f;
    int j = beg + grp;
    for (; j + 8 < end; j += 16) {
        int s0 = srcs[j];
        int s1 = srcs[j + 8];
        uint4 u0 = *(const uint4*)&g1[(size_t)s0 * HDIM + q * 8];
        uint4 u1 = *(const uint4*)&g1[(size_t)s1 * HDIM + q * 8];
        a[0] += bflo(u0.x) + bflo(u1.x); a[1] += bfhi(u0.x) + bfhi(u1.x);
        a[2] += bflo(u0.y) + bflo(u1.y); a[3] += bfhi(u0.y) + bfhi(u1.y);
        a[4] += bflo(u0.z) + bflo(u1.z); a[5] += bfhi(u0.z) + bfhi(u1.z);
        a[6] += bflo(u0.w) + bflo(u1.w); a[7] += bfhi(u0.w) + bfhi(u1.w);
    }
    if (j < end) {
        int s0 = srcs[j];
        uint4 u0 = *(const uint4*)&g1[(size_t)s0 * HDIM + q * 8];
        a[0] += bflo(u0.x); a[1] += bfhi(u0.x);
        a[2] += bflo(u0.y); a[3] += bfhi(u0.y);
        a[4] += bflo(u0.z); a[5] += bfhi(u0.z);
        a[6] += bflo(u0.w); a[7] += bfhi(u0.w);
    }
#pragma unroll
    for (int k = 0; k < 8; k++) {
        a[k] += __shfl_xor(a[k], 8);
        a[k] += __shfl_xor(a[k], 16);
        a[k] += __shfl_xor(a[k], 32);
    }
    if (grp == 0) {
        uint4 us = *(const uint4*)&g1[(size_t)i * HDIM + q * 8];
        float s0 = bflo(us.x), s1 = bfhi(us.x), s2 = bflo(us.y), s3 = bfhi(us.y);
        float s4 = bflo(us.z), s5 = bfhi(us.z), s6 = bflo(us.w), s7 = bfhi(us.w);
        float4 bv0 = *(const float4*)&b1[q * 8];
        float4 bv1 = *(const float4*)&b1[q * 8 + 4];
        float di = dinv[i];
        float o0 = fmaxf(di * (a[0] + s0) + bv0.x, 0.f) * di;
        float o1 = fmaxf(di * (a[1] + s1) + bv0.y, 0.f) * di;
        float o2 = fmaxf(di * (a[2] + s2) + bv0.z, 0.f) * di;
        float o3 = fmaxf(di * (a[3] + s3) + bv0.w, 0.f) * di;
        float o4 = fmaxf(di * (a[4] + s4) + bv1.x, 0.f) * di;
        float o5 = fmaxf(di * (a[5] + s5) + bv1.y, 0.f) * di;
        float o6 = fmaxf(di * (a[6] + s6) + bv1.z, 0.f) * di;
        float o7 = fmaxf(di * (a[7] + s7) + bv1.w, 0.f) * di;
        __hip_bfloat162 p0 = __float22bfloat162_rn(make_float2(o0, o1));
        __hip_bfloat162 p1 = __float22bfloat162_rn(make_float2(o2, o3));
        __hip_bfloat162 p2 = __float22bfloat162_rn(make_float2(o4, o5));
        __hip_bfloat162 p3 = __float22bfloat162_rn(make_float2(o6, o7));
        uint4 w;
        w.x = *(u32*)&p0; w.y = *(u32*)&p1; w.z = *(u32*)&p2; w.w = *(u32*)&p3;
        *(uint4*)&g2[(size_t)i * HDIM + q * 8] = w;
    }
}

// ============ layer-2 gather: pure aggregation, writes h_agg fp32 ============
__global__ __launch_bounds__(256) void k_gather2(const int* __restrict__ rowptr,
                                                 const int* __restrict__ srcs,
                                                 const float* __restrict__ dinv,
                                                 const u16* __restrict__ g2,
                                                 float* __restrict__ hagg, int n) {
    int tid = threadIdx.x;
    int r = tid >> 6, lane = tid & 63;
    int grp = lane >> 3, q = lane & 7;
    int i = blockIdx.x * 4 + r;
    if (i >= n) return;
    int beg = rowptr[i], end = rowptr[i + 1];
    float a[8];
#pragma unroll
    for (int k = 0; k < 8; k++) a[k] = 0.f;
    int j = beg + grp;
    for (; j + 8 < end; j += 16) {
        int s0 = srcs[j];
        int s1 = srcs[j + 8];
        uint4 u0 = *(const uint4*)&g2[(size_t)s0 * HDIM + q * 8];
        uint4 u1 = *(const uint4*)&g2[(size_t)s1 * HDIM + q * 8];
        a[0] += bflo(u0.x) + bflo(u1.x); a[1] += bfhi(u0.x) + bfhi(u1.x);
        a[2] += bflo(u0.y) + bflo(u1.y); a[3] += bfhi(u0.y) + bfhi(u1.y);
        a[4] += bflo(u0.z) + bflo(u1.z); a[5] += bfhi(u0.z) + bfhi(u1.z);
        a[6] += bflo(u0.w) + bflo(u1.w); a[7] += bfhi(u0.w) + bfhi(u1.w);
    }
    if (j < end) {
        int s0 = srcs[j];
        uint4 u0 = *(const uint4*)&g2[(size_t)s0 * HDIM + q * 8];
        a[0] += bflo(u0.x); a[1] += bfhi(u0.x);
        a[2] += bflo(u0.y); a[3] += bfhi(u0.y);
        a[4] += bflo(u0.z); a[5] += bfhi(u0.z);
        a[6] += bflo(u0.w); a[7] += bfhi(u0.w);
    }
#pragma unroll
    for (int k = 0; k < 8; k++) {
        a[k] += __shfl_xor(a[k], 8);
        a[k] += __shfl_xor(a[k], 16);
        a[k] += __shfl_xor(a[k], 32);
    }
    if (grp == 0) {
        uint4 us = *(const uint4*)&g2[(size_t)i * HDIM + q * 8];
        float di = dinv[i];
        float4 o0, o1;
        o0.x = di * (a[0] + bflo(us.x));
        o0.y = di * (a[1] + bfhi(us.x));
        o0.z = di * (a[2] + bflo(us.y));
        o0.w = di * (a[3] + bfhi(us.y));
        o1.x = di * (a[4] + bflo(us.z));
        o1.y = di * (a[5] + bfhi(us.z));
        o1.z = di * (a[6] + bflo(us.w));
        o1.w = di * (a[7] + bfhi(us.w));
        *(float4*)&hagg[(size_t)i * HDIM + q * 8] = o0;
        *(float4*)&hagg[(size_t)i * HDIM + q * 8 + 4] = o1;
    }
}

// ============ GEMM2 (bf16 MFMA, split hi/lo) + epilogue ============
__global__ __launch_bounds__(256) void k_gemm2(const float* __restrict__ hagg,
                                               const short* __restrict__ Whi,
                                               const short* __restrict__ Wlo,
                                               const float* __restrict__ bmu,
                                               const float* __restrict__ bvar,
                                               const float* __restrict__ eps,
                                               float* __restrict__ out, int n) {
    int tid = threadIdx.x;
    int w = tid >> 6, lane = tid & 63;
    int m = lane & 15, kb = lane >> 4;
    int row0 = blockIdx.x * 128 + w * 32;

    short8 ah[2][2], al[2][2];
#pragma unroll
    for (int rb = 0; rb < 2; rb++) {
#pragma unroll
        for (int ks = 0; ks < 2; ks++) {
            int grow = row0 + rb * 16 + m;
            float v[8];
            if (grow < n) {
                const float* base = &hagg[(size_t)grow * HDIM + ks * 32 + kb * 8];
                float4 v0 = *(const float4*)base;
                float4 v1 = *(const float4*)(base + 4);
                v[0] = v0.x; v[1] = v0.y; v[2] = v0.z; v[3] = v0.w;
                v[4] = v1.x; v[5] = v1.y; v[6] = v1.z; v[7] = v1.w;
            } else {
#pragma unroll
                for (int jj = 0; jj < 8; jj++) v[jj] = 0.f;
            }
#pragma unroll
            for (int jj = 0; jj < 8; jj++) {
                __hip_bfloat16 h = __float2bfloat16(v[jj]);
                float hf = __bfloat162float(h);
                __hip_bfloat16 l = __float2bfloat16(v[jj] - hf);
                ah[rb][ks][jj] = *(short*)&h;
                al[rb][ks][jj] = *(short*)&l;
            }
        }
    }

    f32x4 acc[2][8];
#pragma unroll
    for (int rb = 0; rb < 2; rb++)
#pragma unroll
        for (int nt = 0; nt < 8; nt++) acc[rb][nt] = (f32x4){0.f, 0.f, 0.f, 0.f};

#pragma unroll
    for (int nt = 0; nt < 8; nt++) {
#pragma unroll
        for (int ks = 0; ks < 2; ks++) {
            const short* bbase = &Whi[(size_t)(nt * 16 + m) * HDIM + ks * 32 + kb * 8];
            const short* lbase = &Wlo[(size_t)(nt * 16 + m) * HDIM + ks * 32 + kb * 8];
            short8 bh = *(const short8*)bbase;
            short8 bl = *(const short8*)lbase;
#pragma unroll
            for (int rb = 0; rb < 2; rb++) {
                acc[rb][nt] = __builtin_amdgcn_mfma_f32_16x16x32_bf16(ah[rb][ks], bh, acc[rb][nt], 0, 0, 0);
                acc[rb][nt] = __builtin_amdgcn_mfma_f32_16x16x32_bf16(al[rb][ks], bh, acc[rb][nt], 0, 0, 0);
                acc[rb][nt] = __builtin_amdgcn_mfma_f32_16x16x32_bf16(ah[rb][ks], bl, acc[rb][nt], 0, 0, 0);
            }
        }
    }

    size_t nh = (size_t)n * HDIM;
#pragma unroll
    for (int rb = 0; rb < 2; rb++) {
#pragma unroll
        for (int nt = 0; nt < 4; nt++) {
            int c = nt * 16 + m;
            float bm = bmu[c], bv = bvar[c];
#pragma unroll
            for (int reg = 0; reg < 4; reg++) {
                int grow = row0 + rb * 16 + kb * 4 + reg;
                if (grow < n) {
                    float mu = acc[rb][nt][reg] + bm;
                    float va = acc[rb][nt + 4][reg] + bv;
                    float zv = fmaxf(va, 0.f) + log1pf(expf(-fabsf(va)));
                    size_t o = (size_t)grow * HDIM + c;
                    float z = mu + zv * eps[o];
                    out[o] = mu;
                    out[nh + o] = zv;
                    out[2 * nh + o] = z;
                }
            }
        }
    }
}

extern "C" void kernel_launch(void* const* d_in, const int* in_sizes, int n_in,
                              void* d_out, int out_size, void* d_ws, size_t ws_size,
                              hipStream_t stream) {
    const float* x    = (const float*)d_in[0];
    const int*   ei   = (const int*)d_in[1];
    const float* W1   = (const float*)d_in[2];
    const float* b1   = (const float*)d_in[3];
    const float* Wmu  = (const float*)d_in[4];
    const float* bmu  = (const float*)d_in[5];
    const float* Wvar = (const float*)d_in[6];
    const float* bvar = (const float*)d_in[7];
    const float* eps  = (const float*)d_in[8];
    float* out = (float*)d_out;

    int n = in_sizes[0] / IDIM;
    int E = in_sizes[1] / 2;
    const int* src = ei;
    const int* dst = ei + E;

    int NB = (n + CB_NODES - 1) >> CB_SH;   // coarse buckets (<=1024 assumed)

    // workspace layout
    char* p = (char*)d_ws;
    u16* bufB   = (u16*)p;               p += (size_t)n * HDIM * 2;      // g2 bf16
    float* hagg = (float*)p;             p += (size_t)n * HDIM * 4;      // hagg fp32
    u16* bufA   = (u16*)hagg;                                            // g1 bf16 alias
    int2* tmp   = (int2*)hagg;                                           // edge pairs alias (CSR phase)
    int* srcs   = (int*)p;               p += (size_t)E * 4;             // CSR cols
    short* Btg  = (short*)p;             p += (size_t)IDIM * HDIM * 2;   // W1^T bf16
    short* W2hi = (short*)p;             p += (size_t)128 * HDIM * 2;
    short* W2lo = (short*)p;             p += (size_t)128 * HDIM * 2;
    int* rowptr = (int*)p;               p += (size_t)(n + 1) * 4;
    float* dinv = (float*)p;             p += (size_t)n * 4;
    int* gHist  = (int*)p;               p += 1024 * 4;
    int* gcur   = (int*)p;               p += 1024 * 4;
    int* bucketBase = (int*)p;           p += 1025 * 4;

    // --- CSR build (bucketed counting sort; tmp aliases hagg, freed before gemm1) ---
    hipMemsetAsync(gHist, 0, (size_t)NB * sizeof(int), stream);
    k_chist<<<512, 256, 0, stream>>>(dst, gHist, E, NB);
    k_cscan<<<1, 256, 0, stream>>>(gHist, bucketBase, gcur, NB, rowptr, n, E);
    k_partition<<<(E + PCHUNK - 1) / PCHUNK, 256, 0, stream>>>(src, dst, gcur, tmp, E, NB);
    k_finalize<<<NB, 256, 0, stream>>>(tmp, bucketBase, rowptr, dinv, srcs, n);

    // --- weight prep ---
    k_prepB<<<(IDIM * HDIM + 255) / 256, 256, 0, stream>>>(W1, Btg);
    k_prepW2<<<(128 * HDIM + 255) / 256, 256, 0, stream>>>(Wmu, Wvar, W2hi, W2lo);

    // --- layer 1 ---
    k_gemm1<<<(n + GM - 1) / GM, 256, 0, stream>>>(x, Btg, dinv, bufA, n);
    k_gather1<<<(n + 3) / 4, 256, 0, stream>>>(rowptr, srcs, dinv, bufA, b1, bufB, n);

    // --- layer 2: aggregate, then MFMA epilogue GEMM ---
    k_gather2<<<(n + 3) / 4, 256, 0, stream>>>(rowptr, srcs, dinv, bufB, hagg, n);
    k_gemm2<<<(n + 127) / 128, 256, 0, stream>>>(hagg, W2hi, W2lo, bmu, bvar, eps, out, n);
}